// Round 5
// baseline (15756.192 us; speedup 1.0000x reference)
//
#include <hip/hip_runtime.h>
#include <stdint.h>

#define NPART 64
#define NBATCH 32
#define NSEQ 128
#define NEIN 64
#define NHID 256
#define NBLK 256

// ---------------- JAX threefry2x32 (bit-exact) ----------------
__device__ __forceinline__ uint32_t rotl32(uint32_t x, uint32_t d) {
  return (x << d) | (x >> (32u - d));
}

__device__ __forceinline__ void threefry2x32(uint32_t k0, uint32_t k1,
                                             uint32_t& x0, uint32_t& x1) {
  uint32_t k2 = k0 ^ k1 ^ 0x1BD11BDAu;
  x0 += k0; x1 += k1;
#define TFR(r) { x0 += x1; x1 = rotl32(x1, r); x1 ^= x0; }
  TFR(13u) TFR(15u) TFR(26u) TFR(6u)
  x0 += k1; x1 += k2 + 1u;
  TFR(17u) TFR(29u) TFR(16u) TFR(24u)
  x0 += k2; x1 += k0 + 2u;
  TFR(13u) TFR(15u) TFR(26u) TFR(6u)
  x0 += k0; x1 += k1 + 3u;
  TFR(17u) TFR(29u) TFR(16u) TFR(24u)
  x0 += k1; x1 += k2 + 4u;
  TFR(13u) TFR(15u) TFR(26u) TFR(6u)
  x0 += k2; x1 += k0 + 5u;
#undef TFR
}

__device__ __forceinline__ float lreluf(float x) { return x >= 0.f ? x : 0.01f * x; }

// Hand-rolled grid barrier: monotone target, device-scope atomics.
// Safe iff all NBLK blocks are co-resident (1 block/CU at 256 blocks: always).
__device__ __forceinline__ void grid_barrier(unsigned int* cnt, unsigned int target) {
  __syncthreads();
  if (threadIdx.x == 0) {
    __threadfence();                       // release: publish my writes
    atomicAdd(cnt, 1u);                    // device-scope arrive
    unsigned int spins = 0;
    while (__hip_atomic_load(cnt, __ATOMIC_RELAXED, __HIP_MEMORY_SCOPE_AGENT) <
           target) {
      __builtin_amdgcn_s_sleep(2);
      if (++spins > 400000000u) break;     // fail (absmax) rather than hang
    }
    __threadfence();                       // acquire: see others' writes
  }
  __syncthreads();
}

// ---------------- prep: float4 gate-quad repack, state init, key chain -------
__global__ void k_prep(const float* __restrict__ h0, const float* __restrict__ c0,
                       const float* __restrict__ W_ih, const float* __restrict__ W_hh,
                       float* __restrict__ hA, float* __restrict__ cA,
                       float4* __restrict__ Wih4, float4* __restrict__ Whh4,
                       int* __restrict__ idx_buf, uint2* __restrict__ subs,
                       unsigned int* __restrict__ bar_cnt) {
  int tid = blockIdx.x * blockDim.x + threadIdx.x;
  int nthr = gridDim.x * blockDim.x;
  if (tid == 0) *bar_cnt = 0u;
  for (int i = tid; i < NPART * NBATCH * NHID; i += nthr) {
    hA[i] = h0[i];
    cA[i] = c0[i];
  }
  // Wih4[e*256 + j] = (W_ih[j,e], W_ih[256+j,e], W_ih[512+j,e], W_ih[768+j,e])
  for (int i = tid; i < NEIN * NHID; i += nthr) {
    int e = i >> 8, j = i & 255;
    Wih4[i] = make_float4(W_ih[j * NEIN + e], W_ih[(256 + j) * NEIN + e],
                          W_ih[(512 + j) * NEIN + e], W_ih[(768 + j) * NEIN + e]);
  }
  // Whh4[k*256 + j] = (W_hh[j,k], W_hh[256+j,k], W_hh[512+j,k], W_hh[768+j,k])
  for (int i = tid; i < NHID * NHID; i += nthr) {
    int k = i >> 8, j = i & 255;
    Whh4[i] = make_float4(W_hh[j * NHID + k], W_hh[(256 + j) * NHID + k],
                          W_hh[(512 + j) * NHID + k], W_hh[(768 + j) * NHID + k]);
  }
  for (int i = tid; i < NPART * NBATCH; i += nthr) {
    idx_buf[i] = i >> 5;  // identity resample for t=0 gather
  }
  if (tid < NSEQ) {
    // threefry_partitionable split: key' = tf(key,(0,0)), sub = tf(key,(0,1))
    uint32_t k0u = 0u, k1u = 42u, sx = 0u, sy = 0u;
    for (int i = 0; i <= tid; ++i) {
      uint32_t s0 = 0u, s1 = 1u; threefry2x32(k0u, k1u, s0, s1);
      uint32_t n0 = 0u, n1 = 0u; threefry2x32(k0u, k1u, n0, n1);
      sx = s0; sy = s1; k0u = n0; k1u = n1;
    }
    subs[tid] = make_uint2(sx, sy);
  }
}

// ---------------- persistent kernel: all 128 steps, plain launch -------------
// 256 blocks x 256 threads, 1 block/CU (50 KB LDS => always co-resident).
// bid = rb*2 + cbp; rb = b*4 + qg; block computes col tiles cb = cbp*2, cbp*2+1.
// GEMM/pf math verbatim from validated r3 kernels (bit-identical trajectory).
__global__ __launch_bounds__(256, 1)
void k_persist(const float* __restrict__ obs,
               float* __restrict__ hA, float* __restrict__ hB,
               float* __restrict__ cA, float* __restrict__ cB,
               const float4* __restrict__ Wih4, const float4* __restrict__ Whh4,
               const float* __restrict__ b_ih, const float* __restrict__ b_hh,
               const float* __restrict__ W_obs, const float* __restrict__ b_obs_p,
               const float* __restrict__ W_out, const float* __restrict__ b_out_p,
               const uint2* __restrict__ subs, int* __restrict__ idx_buf,
               unsigned int* __restrict__ bar_cnt, float* __restrict__ d_out) {
  __shared__ float4 Wbuf[32 * 64];     // 32 KB
  __shared__ float h_s[16][NHID];      // 16 KB
  __shared__ float obs_s[NEIN];
  __shared__ int src_s[16];
  __shared__ float logp_s[NPART], p1_s[NPART], lg_s[NPART], e_s[NPART], p_cur_s[NPART];
  __shared__ int idx_s[NPART];
  __shared__ float lx_s, ysum_s[4];

  const int tid = threadIdx.x;
  const int bid = blockIdx.x;
  const int cbp = bid & 1;             // column pair: cb in {2*cbp, 2*cbp+1}
  const int rb = bid >> 1;             // 0..127
  const int b = rb >> 2;
  const int qg = rb & 3;
  const bool is_pf = (cbp == 0) && (qg == 0);
  const int lane = tid & 63;
  const int wv = tid >> 6;

  unsigned int bar_target = 0;

  if (is_pf && tid < NPART) p_cur_s[tid] = -4.1588830833596715f;  // fp32(log(1/64))

  for (int t = 0; t < NSEQ; ++t) {
    const float* h_prev = (t & 1) ? hB : hA;
    float* h_out       = (t & 1) ? hA : hB;
    const float* c_prev = (t & 1) ? cB : cA;
    float* c_out       = (t & 1) ? cA : cB;

    // ======== GEMM + LSTM pointwise ========
    if (tid < NEIN) obs_s[tid] = obs[(b * NSEQ + t) * NEIN + tid];
    if (tid < 16) {
      int q = qg * 16 + tid;
      src_s[tid] = idx_buf[q * NBATCH + b] * NBATCH + b;  // resampled source row
    }
    __syncthreads();
    for (int i = tid; i < 16 * (NHID / 4); i += 256) {
      int r = i >> 6, kq = i & 63;
      ((float4*)h_s[r])[kq] = ((const float4*)(h_prev + src_s[r] * NHID))[kq];
    }
    __syncthreads();

    const int rg = wv;                 // wave id = row group (4 rows each)

    for (int cbi = 0; cbi < 2; ++cbi) {
      const int cb = cbp * 2 + cbi;
      const int jglob = cb * 64 + lane;  // h-dim index [0,256)

      float xb[4];
      xb[0] = b_ih[jglob] + b_hh[jglob];
      xb[1] = b_ih[jglob + 256] + b_hh[jglob + 256];
      xb[2] = b_ih[jglob + 512] + b_hh[jglob + 512];
      xb[3] = b_ih[jglob + 768] + b_hh[jglob + 768];
#pragma unroll 8
      for (int e = 0; e < NEIN; ++e) {
        float xv = obs_s[e];
        float4 w = Wih4[e * NHID + jglob];
        xb[0] += xv * w.x;
        xb[1] += xv * w.y;
        xb[2] += xv * w.z;
        xb[3] += xv * w.w;
      }

      float acc[4][4];
#pragma unroll
      for (int rr = 0; rr < 4; ++rr)
#pragma unroll
        for (int g = 0; g < 4; ++g) acc[rr][g] = 0.f;

      const float4* hrow4[4];
#pragma unroll
      for (int rr = 0; rr < 4; ++rr) hrow4[rr] = (const float4*)h_s[rg * 4 + rr];

      for (int c = 0; c < 8; ++c) {    // 8 chunks of 32 k
        const int k0 = c * 32;
        __syncthreads();               // Wbuf reuse guard
        for (int i = tid; i < 32 * 64; i += 256)
          Wbuf[i] = Whh4[(k0 + (i >> 6)) * NHID + cb * 64 + (i & 63)];
        __syncthreads();
#pragma unroll
        for (int k4 = 0; k4 < 8; ++k4) {  // 4 k at a time
          float4 h4[4];
#pragma unroll
          for (int rr = 0; rr < 4; ++rr) h4[rr] = hrow4[rr][(k0 >> 2) + k4];
#pragma unroll
          for (int kk = 0; kk < 4; ++kk) {
            float4 w = Wbuf[(k4 * 4 + kk) * 64 + lane];
#pragma unroll
            for (int rr = 0; rr < 4; ++rr) {
              float hv = ((const float*)&h4[rr])[kk];
              acc[rr][0] += hv * w.x;
              acc[rr][1] += hv * w.y;
              acc[rr][2] += hv * w.z;
              acc[rr][3] += hv * w.w;
            }
          }
        }
      }

#pragma unroll
      for (int rr = 0; rr < 4; ++rr) {
        int q = qg * 16 + rg * 4 + rr;
        int n = q * NBATCH + b;
        float iv = acc[rr][0] + xb[0];
        float fv = acc[rr][1] + xb[1];
        float gv = acc[rr][2] + xb[2];
        float ov = acc[rr][3] + xb[3];
        float cp = c_prev[src_s[rg * 4 + rr] * NHID + jglob];
        float si = 1.f / (1.f + expf(-iv));
        float sf = 1.f / (1.f + expf(-fv));
        float so = 1.f / (1.f + expf(-ov));
        float c1 = sf * cp + si * tanhf(gv);
        float h1 = so * tanhf(c1);
        h_out[n * NHID + jglob] = h1;
        c_out[n * NHID + jglob] = c1;
      }
      __syncthreads();                 // h_s still needed by cbi=1; Wbuf reuse
    }

    bar_target += NBLK;
    grid_barrier(bar_cnt, bar_target);

    // ======== pf phase: obs-loglik, softmax, resample, pf_out, y (32 blocks) ==
    if (is_pf) {
      const float* h1 = h_out;
      if (wv == 0) {
        float v = obs[(b * NSEQ + t) * NEIN + lane] * W_obs[lane];
#pragma unroll
        for (int off = 32; off > 0; off >>= 1) v += __shfl_down(v, off, 64);
        if (lane == 0) lx_s = v + b_obs_p[0];
      }
      for (int qq = 0; qq < 16; ++qq) {
        int q = wv * 16 + qq;
        const float* hrow = h1 + (q * NBATCH + b) * NHID;
        float hp = 0.f;
#pragma unroll
        for (int m = 0; m < 4; ++m)
          hp += hrow[m * 64 + lane] * W_obs[NEIN + m * 64 + lane];
#pragma unroll
        for (int off = 32; off > 0; off >>= 1) hp += __shfl_down(hp, off, 64);
        if (lane == 0) logp_s[q] = hp;
      }
      __syncthreads();

      if (wv == 0) {
        float x = logp_s[lane] + lx_s + p_cur_s[lane];
        float m = x;
#pragma unroll
        for (int off = 32; off > 0; off >>= 1) {
          float o = __shfl_xor(m, off, 64);
          m = o > m ? o : m;
        }
        float s = expf(x - m);
#pragma unroll
        for (int off = 32; off > 0; off >>= 1) s += __shfl_xor(s, off, 64);
        float p1 = x - m - logf(s);
        p1_s[lane] = p1;
        lg_s[lane] = logf(0.1f * expf(p1) + 0.9f / 64.f);
      }
      __syncthreads();

      // categorical: partitionable random_bits, gumbel argmax
      const uint2 sub = subs[t];
      for (int qq = 0; qq < 16; ++qq) {
        int q = wv * 16 + qq;
        uint32_t x0 = 0u;
        uint32_t x1 = (uint32_t)((q * NBATCH + b) * NPART + lane);
        threefry2x32(sub.x, sub.y, x0, x1);
        uint32_t bits = x0 ^ x1;
        uint32_t mant = bits >> 9;
        float u = (mant == 0u) ? 1.17549435e-38f
                               : (float)mant * 1.1920928955078125e-07f;
        float g = -logf(-logf(u));
        float v = g + lg_s[lane];
        int id = lane;
#pragma unroll
        for (int off = 32; off > 0; off >>= 1) {
          float ov = __shfl_xor(v, off, 64);
          int oi = __shfl_xor(id, off, 64);
          if (ov > v || (ov == v && oi < id)) { v = ov; id = oi; }
        }
        if (lane == 0) idx_s[q] = id;
      }
      __syncthreads();

      if (wv == 0) {
        int src = idx_s[lane];
        idx_buf[lane * NBATCH + b] = src;
        float wn = 0.1f * expf(p1_s[src]) + 0.9f / 64.f;
        float lw = logf(wn);
        float m = lw;
#pragma unroll
        for (int off = 32; off > 0; off >>= 1) {
          float o = __shfl_xor(m, off, 64);
          m = o > m ? o : m;
        }
        float s = expf(lw - m);
#pragma unroll
        for (int off = 32; off > 0; off >>= 1) s += __shfl_xor(s, off, 64);
        float pn = lw - m - logf(s);
        p_cur_s[lane] = pn;
        e_s[lane] = expf(pn);
      }
      __syncthreads();

      // pf_out + deterministic y reduction
      float yp = 0.f;
      for (int qq = 0; qq < 16; ++qq) {
        int q = wv * 16 + qq;
        int srow = idx_s[q] * NBATCH + b;
        float pd = 0.f;
#pragma unroll
        for (int m = 0; m < 4; ++m)
          pd += h1[srow * NHID + m * 64 + lane] * W_out[m * 64 + lane];
#pragma unroll
        for (int off = 32; off > 0; off >>= 1) pd += __shfl_down(pd, off, 64);
        if (lane == 0) {
          d_out[NSEQ * NBATCH + t * (NPART * NBATCH) + q * NBATCH + b] =
              lreluf(pd + b_out_p[0]);
          yp += e_s[q] * pd;
        }
      }
      if (lane == 0) ysum_s[wv] = yp;
      __syncthreads();
      if (tid == 0) {
        float y = ((ysum_s[0] + ysum_s[1]) + ysum_s[2]) + ysum_s[3];
        d_out[t * NBATCH + b] = lreluf(y + b_out_p[0]);
      }
    }

    bar_target += NBLK;
    grid_barrier(bar_cnt, bar_target);
  }
}

extern "C" void kernel_launch(void* const* d_in, const int* in_sizes, int n_in,
                              void* d_out, int out_size, void* d_ws, size_t ws_size,
                              hipStream_t stream) {
  const float* obs   = (const float*)d_in[0];
  const float* h0    = (const float*)d_in[1];
  const float* c0    = (const float*)d_in[2];
  const float* W_ih  = (const float*)d_in[3];
  const float* b_ih  = (const float*)d_in[4];
  const float* W_hh  = (const float*)d_in[5];
  const float* b_hh  = (const float*)d_in[6];
  const float* W_obs = (const float*)d_in[7];
  const float* b_obs = (const float*)d_in[8];
  const float* W_out = (const float*)d_in[9];
  const float* b_out = (const float*)d_in[10];
  float* out = (float*)d_out;

  char* w = (char*)d_ws;
  const size_t state = (size_t)NPART * NBATCH * NHID * sizeof(float);  // 2 MB
  float* hA = (float*)w;              w += state;
  float* hB = (float*)w;              w += state;
  float* cA = (float*)w;              w += state;
  float* cB = (float*)w;              w += state;
  uint2* subs = (uint2*)w;            w += NSEQ * sizeof(uint2);
  float4* Wih4 = (float4*)w;          w += NEIN * NHID * sizeof(float4);
  float4* Whh4 = (float4*)w;          w += NHID * NHID * sizeof(float4);
  int* idx_buf = (int*)w;             w += NPART * NBATCH * sizeof(int);
  unsigned int* bar_cnt = (unsigned int*)w;  w += 256;  // barrier counter line

  k_prep<<<dim3(256), dim3(256), 0, stream>>>(h0, c0, W_ih, W_hh, hA, cA, Wih4, Whh4,
                                              idx_buf, subs, bar_cnt);
  k_persist<<<dim3(NBLK), dim3(256), 0, stream>>>(
      obs, hA, hB, cA, cB, Wih4, Whh4, b_ih, b_hh, W_obs, b_obs, W_out, b_out,
      subs, idx_buf, bar_cnt, out);
}

// Round 6
// 12847.391 us; speedup vs baseline: 1.2264x; 1.2264x over previous
//
#include <hip/hip_runtime.h>
#include <stdint.h>

#define NPART 64
#define NBATCH 32
#define NSEQ 128
#define NEIN 64
#define NHID 256
#define NBLK 256

// ---------------- JAX threefry2x32 (bit-exact) ----------------
__device__ __forceinline__ uint32_t rotl32(uint32_t x, uint32_t d) {
  return (x << d) | (x >> (32u - d));
}

__device__ __forceinline__ void threefry2x32(uint32_t k0, uint32_t k1,
                                             uint32_t& x0, uint32_t& x1) {
  uint32_t k2 = k0 ^ k1 ^ 0x1BD11BDAu;
  x0 += k0; x1 += k1;
#define TFR(r) { x0 += x1; x1 = rotl32(x1, r); x1 ^= x0; }
  TFR(13u) TFR(15u) TFR(26u) TFR(6u)
  x0 += k1; x1 += k2 + 1u;
  TFR(17u) TFR(29u) TFR(16u) TFR(24u)
  x0 += k2; x1 += k0 + 2u;
  TFR(13u) TFR(15u) TFR(26u) TFR(6u)
  x0 += k0; x1 += k1 + 3u;
  TFR(17u) TFR(29u) TFR(16u) TFR(24u)
  x0 += k1; x1 += k2 + 4u;
  TFR(13u) TFR(15u) TFR(26u) TFR(6u)
  x0 += k2; x1 += k0 + 5u;
#undef TFR
}

__device__ __forceinline__ float lreluf(float x) { return x >= 0.f ? x : 0.01f * x; }

// Device-scope (agent) relaxed accesses: lower to plain global_load/store with
// device-coherent cache flags — visible across XCDs WITHOUT any L2 wb/inv.
__device__ __forceinline__ float agent_ld(const float* p) {
  return __hip_atomic_load(p, __ATOMIC_RELAXED, __HIP_MEMORY_SCOPE_AGENT);
}
__device__ __forceinline__ void agent_st(float* p, float v) {
  __hip_atomic_store(p, v, __ATOMIC_RELAXED, __HIP_MEMORY_SCOPE_AGENT);
}
__device__ __forceinline__ int agent_ld_i(const int* p) {
  return __hip_atomic_load(p, __ATOMIC_RELAXED, __HIP_MEMORY_SCOPE_AGENT);
}
__device__ __forceinline__ void agent_st_i(int* p, int v) {
  __hip_atomic_store(p, v, __ATOMIC_RELAXED, __HIP_MEMORY_SCOPE_AGENT);
}

// Grid barrier with NO cache-maintenance fences. Correct because all cross-block
// data moves via agent-scope accesses (already at the device coherence point),
// and __syncthreads() drains each wave's vmcnt before s_barrier (all stores
// complete before the arrive).
__device__ __forceinline__ void grid_barrier(unsigned int* cnt, unsigned int target) {
  __builtin_amdgcn_s_waitcnt(0);  // belt & braces: vm/lgkm/exp all drained
  __syncthreads();
  if (threadIdx.x == 0) {
    __hip_atomic_fetch_add(cnt, 1u, __ATOMIC_RELAXED, __HIP_MEMORY_SCOPE_AGENT);
    unsigned int spins = 0;
    while (__hip_atomic_load(cnt, __ATOMIC_RELAXED, __HIP_MEMORY_SCOPE_AGENT) <
           target) {
      __builtin_amdgcn_s_sleep(1);
      if (++spins > 1000000000u) break;  // fail (absmax) rather than hang
    }
  }
  __syncthreads();
}

// ---------------- prep: float4 gate-quad repack, state init, key chain -------
__global__ void k_prep(const float* __restrict__ h0, const float* __restrict__ c0,
                       const float* __restrict__ W_ih, const float* __restrict__ W_hh,
                       float* __restrict__ hA, float* __restrict__ cA,
                       float4* __restrict__ Wih4, float4* __restrict__ Whh4,
                       int* __restrict__ idx_buf, uint2* __restrict__ subs,
                       unsigned int* __restrict__ bar_cnt) {
  int tid = blockIdx.x * blockDim.x + threadIdx.x;
  int nthr = gridDim.x * blockDim.x;
  if (tid == 0)
    __hip_atomic_store(bar_cnt, 0u, __ATOMIC_RELAXED, __HIP_MEMORY_SCOPE_AGENT);
  for (int i = tid; i < NPART * NBATCH * NHID; i += nthr) {
    hA[i] = h0[i];
    cA[i] = c0[i];
  }
  // Wih4[e*256 + j] = (W_ih[j,e], W_ih[256+j,e], W_ih[512+j,e], W_ih[768+j,e])
  for (int i = tid; i < NEIN * NHID; i += nthr) {
    int e = i >> 8, j = i & 255;
    Wih4[i] = make_float4(W_ih[j * NEIN + e], W_ih[(256 + j) * NEIN + e],
                          W_ih[(512 + j) * NEIN + e], W_ih[(768 + j) * NEIN + e]);
  }
  // Whh4[k*256 + j] = (W_hh[j,k], W_hh[256+j,k], W_hh[512+j,k], W_hh[768+j,k])
  for (int i = tid; i < NHID * NHID; i += nthr) {
    int k = i >> 8, j = i & 255;
    Whh4[i] = make_float4(W_hh[j * NHID + k], W_hh[(256 + j) * NHID + k],
                          W_hh[(512 + j) * NHID + k], W_hh[(768 + j) * NHID + k]);
  }
  for (int i = tid; i < NPART * NBATCH; i += nthr) {
    idx_buf[i] = i >> 5;  // identity resample for t=0 gather
  }
  if (tid < NSEQ) {
    // threefry_partitionable split: key' = tf(key,(0,0)), sub = tf(key,(0,1))
    uint32_t k0u = 0u, k1u = 42u, sx = 0u, sy = 0u;
    for (int i = 0; i <= tid; ++i) {
      uint32_t s0 = 0u, s1 = 1u; threefry2x32(k0u, k1u, s0, s1);
      uint32_t n0 = 0u, n1 = 0u; threefry2x32(k0u, k1u, n0, n1);
      sx = s0; sy = s1; k0u = n0; k1u = n1;
    }
    subs[tid] = make_uint2(sx, sy);
  }
}

// ---------------- persistent kernel: all 128 steps, plain launch -------------
// 256 blocks x 256 threads, 1 block/CU (50 KB LDS => always co-resident).
// bid = rb*2 + cbp; rb = b*4 + qg; block computes col tiles cb = cbp*2, cbp*2+1.
// GEMM/pf math value-identical to validated r3/r5 kernels.
__global__ __launch_bounds__(256, 1)
void k_persist(const float* __restrict__ obs,
               float* __restrict__ hA, float* __restrict__ hB,
               float* __restrict__ cA, float* __restrict__ cB,
               const float4* __restrict__ Wih4, const float4* __restrict__ Whh4,
               const float* __restrict__ b_ih, const float* __restrict__ b_hh,
               const float* __restrict__ W_obs, const float* __restrict__ b_obs_p,
               const float* __restrict__ W_out, const float* __restrict__ b_out_p,
               const uint2* __restrict__ subs, int* __restrict__ idx_buf,
               unsigned int* __restrict__ bar_cnt, float* __restrict__ d_out) {
  __shared__ float4 Wbuf[32 * 64];     // 32 KB
  __shared__ float h_s[16][NHID];      // 16 KB
  __shared__ float obs_s[NEIN];
  __shared__ int src_s[16];
  __shared__ float logp_s[NPART], p1_s[NPART], lg_s[NPART], e_s[NPART], p_cur_s[NPART];
  __shared__ int idx_s[NPART];
  __shared__ float lx_s, ysum_s[4];

  const int tid = threadIdx.x;
  const int bid = blockIdx.x;
  const int cbp = bid & 1;             // column pair: cb in {2*cbp, 2*cbp+1}
  const int rb = bid >> 1;             // 0..127
  const int b = rb >> 2;
  const int qg = rb & 3;
  const bool is_pf = (cbp == 0) && (qg == 0);
  const int lane = tid & 63;
  const int wv = tid >> 6;

  unsigned int bar_target = 0;

  if (is_pf && tid < NPART) p_cur_s[tid] = -4.1588830833596715f;  // fp32(log(1/64))

  for (int t = 0; t < NSEQ; ++t) {
    const float* h_prev = (t & 1) ? hB : hA;
    float* h_out       = (t & 1) ? hA : hB;
    const float* c_prev = (t & 1) ? cB : cA;
    float* c_out       = (t & 1) ? cA : cB;

    // ======== GEMM + LSTM pointwise ========
    if (tid < NEIN) obs_s[tid] = obs[(b * NSEQ + t) * NEIN + tid];
    if (tid < 16) {
      int q = qg * 16 + tid;
      src_s[tid] = agent_ld_i(idx_buf + q * NBATCH + b) * NBATCH + b;
    }
    __syncthreads();
    // gather h rows (agent loads: cross-XCD-visible; values identical to r3)
    for (int i = tid; i < 16 * NHID; i += 256) {
      int r = i >> 8, k = i & (NHID - 1);
      h_s[r][k] = agent_ld(h_prev + src_s[r] * NHID + k);
    }
    __syncthreads();

    const int rg = wv;                 // wave id = row group (4 rows each)

    for (int cbi = 0; cbi < 2; ++cbi) {
      const int cb = cbp * 2 + cbi;
      const int jglob = cb * 64 + lane;  // h-dim index [0,256)

      float xb[4];
      xb[0] = b_ih[jglob] + b_hh[jglob];
      xb[1] = b_ih[jglob + 256] + b_hh[jglob + 256];
      xb[2] = b_ih[jglob + 512] + b_hh[jglob + 512];
      xb[3] = b_ih[jglob + 768] + b_hh[jglob + 768];
#pragma unroll 8
      for (int e = 0; e < NEIN; ++e) {
        float xv = obs_s[e];
        float4 w = Wih4[e * NHID + jglob];
        xb[0] += xv * w.x;
        xb[1] += xv * w.y;
        xb[2] += xv * w.z;
        xb[3] += xv * w.w;
      }

      float acc[4][4];
#pragma unroll
      for (int rr = 0; rr < 4; ++rr)
#pragma unroll
        for (int g = 0; g < 4; ++g) acc[rr][g] = 0.f;

      const float4* hrow4[4];
#pragma unroll
      for (int rr = 0; rr < 4; ++rr) hrow4[rr] = (const float4*)h_s[rg * 4 + rr];

      for (int c = 0; c < 8; ++c) {    // 8 chunks of 32 k
        const int k0 = c * 32;
        __syncthreads();               // Wbuf reuse guard
        for (int i = tid; i < 32 * 64; i += 256)
          Wbuf[i] = Whh4[(k0 + (i >> 6)) * NHID + cb * 64 + (i & 63)];
        __syncthreads();
#pragma unroll
        for (int k4 = 0; k4 < 8; ++k4) {  // 4 k at a time
          float4 h4[4];
#pragma unroll
          for (int rr = 0; rr < 4; ++rr) h4[rr] = hrow4[rr][(k0 >> 2) + k4];
#pragma unroll
          for (int kk = 0; kk < 4; ++kk) {
            float4 w = Wbuf[(k4 * 4 + kk) * 64 + lane];
#pragma unroll
            for (int rr = 0; rr < 4; ++rr) {
              float hv = ((const float*)&h4[rr])[kk];
              acc[rr][0] += hv * w.x;
              acc[rr][1] += hv * w.y;
              acc[rr][2] += hv * w.z;
              acc[rr][3] += hv * w.w;
            }
          }
        }
      }

#pragma unroll
      for (int rr = 0; rr < 4; ++rr) {
        int q = qg * 16 + rg * 4 + rr;
        int n = q * NBATCH + b;
        float iv = acc[rr][0] + xb[0];
        float fv = acc[rr][1] + xb[1];
        float gv = acc[rr][2] + xb[2];
        float ov = acc[rr][3] + xb[3];
        float cp = agent_ld(c_prev + src_s[rg * 4 + rr] * NHID + jglob);
        float si = 1.f / (1.f + expf(-iv));
        float sf = 1.f / (1.f + expf(-fv));
        float so = 1.f / (1.f + expf(-ov));
        float c1 = sf * cp + si * tanhf(gv);
        float h1 = so * tanhf(c1);
        agent_st(h_out + n * NHID + jglob, h1);
        agent_st(c_out + n * NHID + jglob, c1);
      }
      __syncthreads();                 // h_s still needed by cbi=1; Wbuf reuse
    }

    bar_target += NBLK;
    grid_barrier(bar_cnt, bar_target);

    // ======== pf phase: obs-loglik, softmax, resample, pf_out, y (32 blocks) ==
    if (is_pf) {
      const float* h1 = h_out;
      if (wv == 0) {
        float v = obs[(b * NSEQ + t) * NEIN + lane] * W_obs[lane];
#pragma unroll
        for (int off = 32; off > 0; off >>= 1) v += __shfl_down(v, off, 64);
        if (lane == 0) lx_s = v + b_obs_p[0];
      }
      for (int qq = 0; qq < 16; ++qq) {
        int q = wv * 16 + qq;
        const float* hrow = h1 + (q * NBATCH + b) * NHID;
        float hp = 0.f;
#pragma unroll
        for (int m = 0; m < 4; ++m)
          hp += agent_ld(hrow + m * 64 + lane) * W_obs[NEIN + m * 64 + lane];
#pragma unroll
        for (int off = 32; off > 0; off >>= 1) hp += __shfl_down(hp, off, 64);
        if (lane == 0) logp_s[q] = hp;
      }
      __syncthreads();

      if (wv == 0) {
        float x = logp_s[lane] + lx_s + p_cur_s[lane];
        float m = x;
#pragma unroll
        for (int off = 32; off > 0; off >>= 1) {
          float o = __shfl_xor(m, off, 64);
          m = o > m ? o : m;
        }
        float s = expf(x - m);
#pragma unroll
        for (int off = 32; off > 0; off >>= 1) s += __shfl_xor(s, off, 64);
        float p1 = x - m - logf(s);
        p1_s[lane] = p1;
        lg_s[lane] = logf(0.1f * expf(p1) + 0.9f / 64.f);
      }
      __syncthreads();

      // categorical: partitionable random_bits, gumbel argmax
      const uint2 sub = subs[t];
      for (int qq = 0; qq < 16; ++qq) {
        int q = wv * 16 + qq;
        uint32_t x0 = 0u;
        uint32_t x1 = (uint32_t)((q * NBATCH + b) * NPART + lane);
        threefry2x32(sub.x, sub.y, x0, x1);
        uint32_t bits = x0 ^ x1;
        uint32_t mant = bits >> 9;
        float u = (mant == 0u) ? 1.17549435e-38f
                               : (float)mant * 1.1920928955078125e-07f;
        float g = -logf(-logf(u));
        float v = g + lg_s[lane];
        int id = lane;
#pragma unroll
        for (int off = 32; off > 0; off >>= 1) {
          float ov = __shfl_xor(v, off, 64);
          int oi = __shfl_xor(id, off, 64);
          if (ov > v || (ov == v && oi < id)) { v = ov; id = oi; }
        }
        if (lane == 0) idx_s[q] = id;
      }
      __syncthreads();

      if (wv == 0) {
        int src = idx_s[lane];
        agent_st_i(idx_buf + lane * NBATCH + b, src);
        float wn = 0.1f * expf(p1_s[src]) + 0.9f / 64.f;
        float lw = logf(wn);
        float m = lw;
#pragma unroll
        for (int off = 32; off > 0; off >>= 1) {
          float o = __shfl_xor(m, off, 64);
          m = o > m ? o : m;
        }
        float s = expf(lw - m);
#pragma unroll
        for (int off = 32; off > 0; off >>= 1) s += __shfl_xor(s, off, 64);
        float pn = lw - m - logf(s);
        p_cur_s[lane] = pn;
        e_s[lane] = expf(pn);
      }
      __syncthreads();

      // pf_out + deterministic y reduction
      float yp = 0.f;
      for (int qq = 0; qq < 16; ++qq) {
        int q = wv * 16 + qq;
        int srow = idx_s[q] * NBATCH + b;
        float pd = 0.f;
#pragma unroll
        for (int m = 0; m < 4; ++m)
          pd += agent_ld(h1 + srow * NHID + m * 64 + lane) * W_out[m * 64 + lane];
#pragma unroll
        for (int off = 32; off > 0; off >>= 1) pd += __shfl_down(pd, off, 64);
        if (lane == 0) {
          d_out[NSEQ * NBATCH + t * (NPART * NBATCH) + q * NBATCH + b] =
              lreluf(pd + b_out_p[0]);
          yp += e_s[q] * pd;
        }
      }
      if (lane == 0) ysum_s[wv] = yp;
      __syncthreads();
      if (tid == 0) {
        float y = ((ysum_s[0] + ysum_s[1]) + ysum_s[2]) + ysum_s[3];
        d_out[t * NBATCH + b] = lreluf(y + b_out_p[0]);
      }
    }

    bar_target += NBLK;
    grid_barrier(bar_cnt, bar_target);
  }
}

extern "C" void kernel_launch(void* const* d_in, const int* in_sizes, int n_in,
                              void* d_out, int out_size, void* d_ws, size_t ws_size,
                              hipStream_t stream) {
  const float* obs   = (const float*)d_in[0];
  const float* h0    = (const float*)d_in[1];
  const float* c0    = (const float*)d_in[2];
  const float* W_ih  = (const float*)d_in[3];
  const float* b_ih  = (const float*)d_in[4];
  const float* W_hh  = (const float*)d_in[5];
  const float* b_hh  = (const float*)d_in[6];
  const float* W_obs = (const float*)d_in[7];
  const float* b_obs = (const float*)d_in[8];
  const float* W_out = (const float*)d_in[9];
  const float* b_out = (const float*)d_in[10];
  float* out = (float*)d_out;

  char* w = (char*)d_ws;
  const size_t state = (size_t)NPART * NBATCH * NHID * sizeof(float);  // 2 MB
  float* hA = (float*)w;              w += state;
  float* hB = (float*)w;              w += state;
  float* cA = (float*)w;              w += state;
  float* cB = (float*)w;              w += state;
  uint2* subs = (uint2*)w;            w += NSEQ * sizeof(uint2);
  float4* Wih4 = (float4*)w;          w += NEIN * NHID * sizeof(float4);
  float4* Whh4 = (float4*)w;          w += NHID * NHID * sizeof(float4);
  int* idx_buf = (int*)w;             w += NPART * NBATCH * sizeof(int);
  unsigned int* bar_cnt = (unsigned int*)w;  w += 256;  // barrier counter line

  k_prep<<<dim3(256), dim3(256), 0, stream>>>(h0, c0, W_ih, W_hh, hA, cA, Wih4, Whh4,
                                              idx_buf, subs, bar_cnt);
  k_persist<<<dim3(NBLK), dim3(256), 0, stream>>>(
      obs, hA, hB, cA, cB, Wih4, Whh4, b_ih, b_hh, W_obs, b_obs, W_out, b_out,
      subs, idx_buf, bar_cnt, out);
}

// Round 7
// 10409.769 us; speedup vs baseline: 1.5136x; 1.2342x over previous
//
#include <hip/hip_runtime.h>
#include <stdint.h>

#define NPART 64
#define NBATCH 32
#define NSEQ 128
#define NEIN 64
#define NHID 256
#define NBLK 256

// ---------------- JAX threefry2x32 (bit-exact) ----------------
__device__ __forceinline__ uint32_t rotl32(uint32_t x, uint32_t d) {
  return (x << d) | (x >> (32u - d));
}

__device__ __forceinline__ void threefry2x32(uint32_t k0, uint32_t k1,
                                             uint32_t& x0, uint32_t& x1) {
  uint32_t k2 = k0 ^ k1 ^ 0x1BD11BDAu;
  x0 += k0; x1 += k1;
#define TFR(r) { x0 += x1; x1 = rotl32(x1, r); x1 ^= x0; }
  TFR(13u) TFR(15u) TFR(26u) TFR(6u)
  x0 += k1; x1 += k2 + 1u;
  TFR(17u) TFR(29u) TFR(16u) TFR(24u)
  x0 += k2; x1 += k0 + 2u;
  TFR(13u) TFR(15u) TFR(26u) TFR(6u)
  x0 += k0; x1 += k1 + 3u;
  TFR(17u) TFR(29u) TFR(16u) TFR(24u)
  x0 += k1; x1 += k2 + 4u;
  TFR(13u) TFR(15u) TFR(26u) TFR(6u)
  x0 += k2; x1 += k0 + 5u;
#undef TFR
}

__device__ __forceinline__ float lreluf(float x) { return x >= 0.f ? x : 0.01f * x; }

// Agent-scope relaxed accesses: coherent across XCDs (bypass L1/L2, served by IC).
__device__ __forceinline__ float agent_ld(const float* p) {
  return __hip_atomic_load(p, __ATOMIC_RELAXED, __HIP_MEMORY_SCOPE_AGENT);
}
__device__ __forceinline__ void agent_st(float* p, float v) {
  __hip_atomic_store(p, v, __ATOMIC_RELAXED, __HIP_MEMORY_SCOPE_AGENT);
}
__device__ __forceinline__ unsigned long long agent_ld_u64(const unsigned long long* p) {
  return __hip_atomic_load(p, __ATOMIC_RELAXED, __HIP_MEMORY_SCOPE_AGENT);
}

// Two-level grid barrier: 8 group lines x 32 arrivals -> 8 leader atomics ->
// one release epoch, polled read-only. No cache-maintenance fences (all
// cross-block data moves via agent-scope accesses; vmcnt drained before arrive).
__device__ __forceinline__ void grid_barrier(unsigned int* grp_cnt,
                                             unsigned int* lead_cnt,
                                             unsigned int* release,
                                             int bid, unsigned int step) {
  __builtin_amdgcn_s_waitcnt(0);
  __syncthreads();
  if (threadIdx.x == 0) {
    unsigned int* my = grp_cnt + (bid >> 5) * 64;  // 256B-spaced lines
    unsigned int old =
        __hip_atomic_fetch_add(my, 1u, __ATOMIC_RELAXED, __HIP_MEMORY_SCOPE_AGENT);
    if (old == step * 32u - 1u) {  // last arriver of my group
      unsigned int g = __hip_atomic_fetch_add(lead_cnt, 1u, __ATOMIC_RELAXED,
                                              __HIP_MEMORY_SCOPE_AGENT);
      if (g == step * 8u - 1u)
        __hip_atomic_store(release, step, __ATOMIC_RELAXED,
                           __HIP_MEMORY_SCOPE_AGENT);
    }
    unsigned int spins = 0;
    while (__hip_atomic_load(release, __ATOMIC_RELAXED,
                             __HIP_MEMORY_SCOPE_AGENT) < step) {
      __builtin_amdgcn_s_sleep(4);
      if (++spins > 100000000u) break;  // fail (absmax) rather than hang
    }
  }
  __syncthreads();
}

// ---------------- prep: float4 gate-quad repack, state init, key chain -------
__global__ void k_prep(const float* __restrict__ h0, const float* __restrict__ c0,
                       const float* __restrict__ W_ih, const float* __restrict__ W_hh,
                       float* __restrict__ hA, float* __restrict__ cA,
                       float4* __restrict__ Wih4, float4* __restrict__ Whh4,
                       uint2* __restrict__ subs, unsigned int* __restrict__ bar_mem) {
  int tid = blockIdx.x * blockDim.x + threadIdx.x;
  int nthr = gridDim.x * blockDim.x;
  if (tid < 8 * 64 + 64)  // group lines + leader cnt + release
    __hip_atomic_store(bar_mem + tid, 0u, __ATOMIC_RELAXED, __HIP_MEMORY_SCOPE_AGENT);
  for (int i = tid; i < NPART * NBATCH * NHID; i += nthr) {
    hA[i] = h0[i];
    cA[i] = c0[i];
  }
  // Wih4[e*256 + j] = (W_ih[j,e], W_ih[256+j,e], W_ih[512+j,e], W_ih[768+j,e])
  for (int i = tid; i < NEIN * NHID; i += nthr) {
    int e = i >> 8, j = i & 255;
    Wih4[i] = make_float4(W_ih[j * NEIN + e], W_ih[(256 + j) * NEIN + e],
                          W_ih[(512 + j) * NEIN + e], W_ih[(768 + j) * NEIN + e]);
  }
  // Whh4[k*256 + j] = (W_hh[j,k], W_hh[256+j,k], W_hh[512+j,k], W_hh[768+j,k])
  for (int i = tid; i < NHID * NHID; i += nthr) {
    int k = i >> 8, j = i & 255;
    Whh4[i] = make_float4(W_hh[j * NHID + k], W_hh[(256 + j) * NHID + k],
                          W_hh[(512 + j) * NHID + k], W_hh[(768 + j) * NHID + k]);
  }
  if (tid < NSEQ) {
    // threefry_partitionable split: key' = tf(key,(0,0)), sub = tf(key,(0,1))
    uint32_t k0u = 0u, k1u = 42u, sx = 0u, sy = 0u;
    for (int i = 0; i <= tid; ++i) {
      uint32_t s0 = 0u, s1 = 1u; threefry2x32(k0u, k1u, s0, s1);
      uint32_t n0 = 0u, n1 = 0u; threefry2x32(k0u, k1u, n0, n1);
      sx = s0; sy = s1; k0u = n0; k1u = n1;
    }
    subs[tid] = make_uint2(sx, sy);
  }
}

// pf phase for step tm1 (math verbatim r6, h1 sourced from LDS). Computed
// redundantly by every block of batch b (deterministic -> identical results);
// only is_des writes outputs. Requires h1_s staged; leaves idx_s/p_cur_s/e_s set.
__device__ __forceinline__ void pf_phase(
    int tm1, int b, bool is_des, const float* __restrict__ obs,
    const float* __restrict__ W_obs, const float* __restrict__ b_obs_p,
    const float* __restrict__ W_out, const float* __restrict__ b_out_p,
    const uint2* __restrict__ subs, float* __restrict__ d_out,
    float (*h1_s)[NHID], float* logp_s, float* p1_s, float* lg_s, float* e_s,
    float* p_cur_s, int* idx_s, float* lx_s, float* ysum_s) {
  const int tid = threadIdx.x;
  const int lane = tid & 63;
  const int wv = tid >> 6;

  if (wv == 0) {
    float v = obs[(b * NSEQ + tm1) * NEIN + lane] * W_obs[lane];
#pragma unroll
    for (int off = 32; off > 0; off >>= 1) v += __shfl_down(v, off, 64);
    if (lane == 0) *lx_s = v + b_obs_p[0];
  }
  for (int qq = 0; qq < 16; ++qq) {
    int q = wv * 16 + qq;
    float hp = 0.f;
#pragma unroll
    for (int m = 0; m < 4; ++m)
      hp += h1_s[q][m * 64 + lane] * W_obs[NEIN + m * 64 + lane];
#pragma unroll
    for (int off = 32; off > 0; off >>= 1) hp += __shfl_down(hp, off, 64);
    if (lane == 0) logp_s[q] = hp;
  }
  __syncthreads();

  if (wv == 0) {
    float x = logp_s[lane] + *lx_s + p_cur_s[lane];
    float m = x;
#pragma unroll
    for (int off = 32; off > 0; off >>= 1) {
      float o = __shfl_xor(m, off, 64);
      m = o > m ? o : m;
    }
    float s = expf(x - m);
#pragma unroll
    for (int off = 32; off > 0; off >>= 1) s += __shfl_xor(s, off, 64);
    float p1 = x - m - logf(s);
    p1_s[lane] = p1;
    lg_s[lane] = logf(0.1f * expf(p1) + 0.9f / 64.f);
  }
  __syncthreads();

  // categorical: partitionable random_bits, gumbel argmax
  const uint2 sub = subs[tm1];
  for (int qq = 0; qq < 16; ++qq) {
    int q = wv * 16 + qq;
    uint32_t x0 = 0u;
    uint32_t x1 = (uint32_t)((q * NBATCH + b) * NPART + lane);
    threefry2x32(sub.x, sub.y, x0, x1);
    uint32_t bits = x0 ^ x1;
    uint32_t mant = bits >> 9;
    float u = (mant == 0u) ? 1.17549435e-38f
                           : (float)mant * 1.1920928955078125e-07f;
    float g = -logf(-logf(u));
    float v = g + lg_s[lane];
    int id = lane;
#pragma unroll
    for (int off = 32; off > 0; off >>= 1) {
      float ov = __shfl_xor(v, off, 64);
      int oi = __shfl_xor(id, off, 64);
      if (ov > v || (ov == v && oi < id)) { v = ov; id = oi; }
    }
    if (lane == 0) idx_s[q] = id;
  }
  __syncthreads();

  if (wv == 0) {
    int src = idx_s[lane];
    float wn = 0.1f * expf(p1_s[src]) + 0.9f / 64.f;
    float lw = logf(wn);
    float m = lw;
#pragma unroll
    for (int off = 32; off > 0; off >>= 1) {
      float o = __shfl_xor(m, off, 64);
      m = o > m ? o : m;
    }
    float s = expf(lw - m);
#pragma unroll
    for (int off = 32; off > 0; off >>= 1) s += __shfl_xor(s, off, 64);
    float pn = lw - m - logf(s);
    p_cur_s[lane] = pn;
    e_s[lane] = expf(pn);
  }
  __syncthreads();

  // pf_out + deterministic y reduction (designated block only writes)
  if (is_des) {
    float yp = 0.f;
    for (int qq = 0; qq < 16; ++qq) {
      int q = wv * 16 + qq;
      int srow = idx_s[q];
      float pd = 0.f;
#pragma unroll
      for (int m = 0; m < 4; ++m)
        pd += h1_s[srow][m * 64 + lane] * W_out[m * 64 + lane];
#pragma unroll
      for (int off = 32; off > 0; off >>= 1) pd += __shfl_down(pd, off, 64);
      if (lane == 0) {
        d_out[NSEQ * NBATCH + tm1 * (NPART * NBATCH) + q * NBATCH + b] =
            lreluf(pd + b_out_p[0]);
        yp += e_s[q] * pd;
      }
    }
    if (lane == 0) ysum_s[wv] = yp;
    __syncthreads();
    if (tid == 0) {
      float y = ((ysum_s[0] + ysum_s[1]) + ysum_s[2]) + ysum_s[3];
      d_out[tm1 * NBATCH + b] = lreluf(y + b_out_p[0]);
    }
  }
}

// ---------------- persistent kernel: all 128 steps, ONE barrier/step ---------
// 256 blocks x 256 threads, 1 block/CU. bid = b*8 + qg*2 + cbp.
// Each block: stages full h1 of its batch to LDS, computes pf redundantly,
// gathers locally, GEMMs 16 rows x 128 cols. Trajectory bit-identical to r6.
__global__ __launch_bounds__(256, 1)
void k_persist(const float* __restrict__ obs,
               float* __restrict__ hA, float* __restrict__ hB,
               float* __restrict__ cA, float* __restrict__ cB,
               const float4* __restrict__ Wih4, const float4* __restrict__ Whh4,
               const float* __restrict__ b_ih, const float* __restrict__ b_hh,
               const float* __restrict__ W_obs, const float* __restrict__ b_obs_p,
               const float* __restrict__ W_out, const float* __restrict__ b_out_p,
               const uint2* __restrict__ subs, unsigned int* __restrict__ bar_mem,
               float* __restrict__ d_out) {
  __shared__ __align__(16) float h1_s[NPART][NHID];  // 64 KB: full batch h
  __shared__ float4 Wbuf[32 * 64];                   // 32 KB
  __shared__ float obs_s[NEIN];
  __shared__ float logp_s[NPART], p1_s[NPART], lg_s[NPART], e_s[NPART],
      p_cur_s[NPART];
  __shared__ int idx_s[NPART];
  __shared__ float lx_s, ysum_s[4];

  unsigned int* grp_cnt = bar_mem;           // 8 lines x 64 u32
  unsigned int* lead_cnt = bar_mem + 8 * 64;
  unsigned int* release = bar_mem + 8 * 64 + 16;

  const int tid = threadIdx.x;
  const int bid = blockIdx.x;
  const int cbp = bid & 1;
  const int qg = (bid >> 1) & 3;
  const int b = bid >> 3;
  const bool is_des = ((bid & 7) == 0);
  const int lane = tid & 63;
  const int wv = tid >> 6;

  if (tid < NPART) p_cur_s[tid] = -4.1588830833596715f;  // fp32(log(1/64))

  for (int t = 0; t < NSEQ; ++t) {
    const float* hsrc = (t & 1) ? hB : hA;   // h written at t-1 (t=0: h0)
    const float* csrc = (t & 1) ? cB : cA;
    float* hdst = (t & 1) ? hA : hB;
    float* cdst = (t & 1) ? cA : cB;

    // stage full batch h1 into LDS (agent 8B loads; coherent cross-XCD)
    {
      const unsigned long long* h8 = (const unsigned long long*)hsrc;
      unsigned long long* l8 = (unsigned long long*)h1_s;
      for (int i = tid; i < NPART * (NHID / 2); i += 256) {
        int q = i >> 7, c8 = i & 127;
        l8[q * 128 + c8] = agent_ld_u64(h8 + (q * NBATCH + b) * (NHID / 2) + c8);
      }
    }
    __syncthreads();

    if (t == 0) {
      if (tid < NPART) idx_s[tid] = tid;  // identity resample for t=0
      __syncthreads();
    } else {
      pf_phase(t - 1, b, is_des, obs, W_obs, b_obs_p, W_out, b_out_p, subs,
               d_out, h1_s, logp_s, p1_s, lg_s, e_s, p_cur_s, idx_s, &lx_s,
               ysum_s);
    }

    // ======== GEMM + LSTM pointwise (obs[t]) ========
    if (tid < NEIN) obs_s[tid] = obs[(b * NSEQ + t) * NEIN + tid];
    __syncthreads();

    const int rg = wv;  // wave id = row group (4 rows each)
    int srow[4];
#pragma unroll
    for (int rr = 0; rr < 4; ++rr) srow[rr] = idx_s[qg * 16 + rg * 4 + rr];

    for (int cbi = 0; cbi < 2; ++cbi) {
      const int cb = cbp * 2 + cbi;
      const int jglob = cb * 64 + lane;

      float xb[4];
      xb[0] = b_ih[jglob] + b_hh[jglob];
      xb[1] = b_ih[jglob + 256] + b_hh[jglob + 256];
      xb[2] = b_ih[jglob + 512] + b_hh[jglob + 512];
      xb[3] = b_ih[jglob + 768] + b_hh[jglob + 768];
#pragma unroll 8
      for (int e = 0; e < NEIN; ++e) {
        float xv = obs_s[e];
        float4 w = Wih4[e * NHID + jglob];
        xb[0] += xv * w.x;
        xb[1] += xv * w.y;
        xb[2] += xv * w.z;
        xb[3] += xv * w.w;
      }

      float acc[4][4];
#pragma unroll
      for (int rr = 0; rr < 4; ++rr)
#pragma unroll
        for (int g = 0; g < 4; ++g) acc[rr][g] = 0.f;

      const float4* hrow4[4];
#pragma unroll
      for (int rr = 0; rr < 4; ++rr) hrow4[rr] = (const float4*)h1_s[srow[rr]];

      for (int c = 0; c < 8; ++c) {  // 8 chunks of 32 k
        const int k0 = c * 32;
        __syncthreads();             // Wbuf reuse guard
        for (int i = tid; i < 32 * 64; i += 256)
          Wbuf[i] = Whh4[(k0 + (i >> 6)) * NHID + cb * 64 + (i & 63)];
        __syncthreads();
#pragma unroll
        for (int k4 = 0; k4 < 8; ++k4) {  // 4 k at a time
          float4 h4[4];
#pragma unroll
          for (int rr = 0; rr < 4; ++rr) h4[rr] = hrow4[rr][(k0 >> 2) + k4];
#pragma unroll
          for (int kk = 0; kk < 4; ++kk) {
            float4 w = Wbuf[(k4 * 4 + kk) * 64 + lane];
#pragma unroll
            for (int rr = 0; rr < 4; ++rr) {
              float hv = ((const float*)&h4[rr])[kk];
              acc[rr][0] += hv * w.x;
              acc[rr][1] += hv * w.y;
              acc[rr][2] += hv * w.z;
              acc[rr][3] += hv * w.w;
            }
          }
        }
      }

#pragma unroll
      for (int rr = 0; rr < 4; ++rr) {
        int q = qg * 16 + rg * 4 + rr;
        int n = q * NBATCH + b;
        float iv = acc[rr][0] + xb[0];
        float fv = acc[rr][1] + xb[1];
        float gv = acc[rr][2] + xb[2];
        float ov = acc[rr][3] + xb[3];
        float cp = agent_ld(csrc + (srow[rr] * NBATCH + b) * NHID + jglob);
        float si = 1.f / (1.f + expf(-iv));
        float sf = 1.f / (1.f + expf(-fv));
        float so = 1.f / (1.f + expf(-ov));
        float c1 = sf * cp + si * tanhf(gv);
        float h1 = so * tanhf(c1);
        agent_st(hdst + n * NHID + jglob, h1);
        agent_st(cdst + n * NHID + jglob, c1);
      }
      __syncthreads();  // h1_s/Wbuf reuse for cbi=1
    }

    grid_barrier(grp_cnt, lead_cnt, release, bid, (unsigned int)(t + 1));
  }

  // tail: pf for t = 127 (h written at t=127 lives in hA since 127&1==1)
  {
    const float* hsrc = hA;
    const unsigned long long* h8 = (const unsigned long long*)hsrc;
    unsigned long long* l8 = (unsigned long long*)h1_s;
    for (int i = tid; i < NPART * (NHID / 2); i += 256) {
      int q = i >> 7, c8 = i & 127;
      l8[q * 128 + c8] = agent_ld_u64(h8 + (q * NBATCH + b) * (NHID / 2) + c8);
    }
    __syncthreads();
    pf_phase(NSEQ - 1, b, is_des, obs, W_obs, b_obs_p, W_out, b_out_p, subs,
             d_out, h1_s, logp_s, p1_s, lg_s, e_s, p_cur_s, idx_s, &lx_s,
             ysum_s);
  }
}

extern "C" void kernel_launch(void* const* d_in, const int* in_sizes, int n_in,
                              void* d_out, int out_size, void* d_ws, size_t ws_size,
                              hipStream_t stream) {
  const float* obs   = (const float*)d_in[0];
  const float* h0    = (const float*)d_in[1];
  const float* c0    = (const float*)d_in[2];
  const float* W_ih  = (const float*)d_in[3];
  const float* b_ih  = (const float*)d_in[4];
  const float* W_hh  = (const float*)d_in[5];
  const float* b_hh  = (const float*)d_in[6];
  const float* W_obs = (const float*)d_in[7];
  const float* b_obs = (const float*)d_in[8];
  const float* W_out = (const float*)d_in[9];
  const float* b_out = (const float*)d_in[10];
  float* out = (float*)d_out;

  char* w = (char*)d_ws;
  const size_t state = (size_t)NPART * NBATCH * NHID * sizeof(float);  // 2 MB
  float* hA = (float*)w;              w += state;
  float* hB = (float*)w;              w += state;
  float* cA = (float*)w;              w += state;
  float* cB = (float*)w;              w += state;
  uint2* subs = (uint2*)w;            w += NSEQ * sizeof(uint2);
  float4* Wih4 = (float4*)w;          w += NEIN * NHID * sizeof(float4);
  float4* Whh4 = (float4*)w;          w += NHID * NHID * sizeof(float4);
  unsigned int* bar_mem = (unsigned int*)w;  w += (8 * 64 + 64) * sizeof(unsigned int);

  k_prep<<<dim3(256), dim3(256), 0, stream>>>(h0, c0, W_ih, W_hh, hA, cA, Wih4, Whh4,
                                              subs, bar_mem);
  k_persist<<<dim3(NBLK), dim3(256), 0, stream>>>(
      obs, hA, hB, cA, cB, Wih4, Whh4, b_ih, b_hh, W_obs, b_obs, W_out, b_out,
      subs, bar_mem, out);
}

// Round 8
// 9438.714 us; speedup vs baseline: 1.6693x; 1.1029x over previous
//
#include <hip/hip_runtime.h>
#include <stdint.h>

#define NPART 64
#define NBATCH 32
#define NSEQ 128
#define NEIN 64
#define NHID 256
#define NBLK 256

using f32x4 = __attribute__((ext_vector_type(4))) float;

// ---------------- JAX threefry2x32 (bit-exact) ----------------
__device__ __forceinline__ uint32_t rotl32(uint32_t x, uint32_t d) {
  return (x << d) | (x >> (32u - d));
}

__device__ __forceinline__ void threefry2x32(uint32_t k0, uint32_t k1,
                                             uint32_t& x0, uint32_t& x1) {
  uint32_t k2 = k0 ^ k1 ^ 0x1BD11BDAu;
  x0 += k0; x1 += k1;
#define TFR(r) { x0 += x1; x1 = rotl32(x1, r); x1 ^= x0; }
  TFR(13u) TFR(15u) TFR(26u) TFR(6u)
  x0 += k1; x1 += k2 + 1u;
  TFR(17u) TFR(29u) TFR(16u) TFR(24u)
  x0 += k2; x1 += k0 + 2u;
  TFR(13u) TFR(15u) TFR(26u) TFR(6u)
  x0 += k0; x1 += k1 + 3u;
  TFR(17u) TFR(29u) TFR(16u) TFR(24u)
  x0 += k1; x1 += k2 + 4u;
  TFR(13u) TFR(15u) TFR(26u) TFR(6u)
  x0 += k2; x1 += k0 + 5u;
#undef TFR
}

__device__ __forceinline__ float lreluf(float x) { return x >= 0.f ? x : 0.01f * x; }

// Device-coherent wide accesses: sc0 sc1 = bypass L1 + per-XCD L2, served by
// IC (same coherence point agent atomics use) — but issued as plain vmcnt
// loads/stores so many can be in flight; one s_waitcnt drains the batch.
__device__ __forceinline__ void dc_load16(f32x4& dst, const float* p) {
  asm volatile("global_load_dwordx4 %0, %1, off sc0 sc1" : "=v"(dst) : "v"(p));
}
__device__ __forceinline__ void dc_store4(float* p, float v) {
  asm volatile("global_store_dword %0, %1, off sc0 sc1" :: "v"(p), "v"(v)
               : "memory");
}
__device__ __forceinline__ void dc_drain() {
  asm volatile("s_waitcnt vmcnt(0)" ::: "memory");
}

// Two-level grid barrier: 8 group lines x 32 arrivals -> 8 leader atomics ->
// one release epoch, polled read-only (validated r7).
__device__ __forceinline__ void grid_barrier(unsigned int* grp_cnt,
                                             unsigned int* lead_cnt,
                                             unsigned int* release,
                                             int bid, unsigned int step) {
  __builtin_amdgcn_s_waitcnt(0);  // drain asm stores + everything else
  __syncthreads();
  if (threadIdx.x == 0) {
    unsigned int* my = grp_cnt + (bid >> 5) * 64;  // 256B-spaced lines
    unsigned int old =
        __hip_atomic_fetch_add(my, 1u, __ATOMIC_RELAXED, __HIP_MEMORY_SCOPE_AGENT);
    if (old == step * 32u - 1u) {  // last arriver of my group
      unsigned int g = __hip_atomic_fetch_add(lead_cnt, 1u, __ATOMIC_RELAXED,
                                              __HIP_MEMORY_SCOPE_AGENT);
      if (g == step * 8u - 1u)
        __hip_atomic_store(release, step, __ATOMIC_RELAXED,
                           __HIP_MEMORY_SCOPE_AGENT);
    }
    unsigned int spins = 0;
    while (__hip_atomic_load(release, __ATOMIC_RELAXED,
                             __HIP_MEMORY_SCOPE_AGENT) < step) {
      __builtin_amdgcn_s_sleep(4);
      if (++spins > 100000000u) break;  // fail (absmax) rather than hang
    }
  }
  __syncthreads();
}

// ---------------- prep: float4 gate-quad repack, state init, key chain -------
__global__ void k_prep(const float* __restrict__ h0, const float* __restrict__ c0,
                       const float* __restrict__ W_ih, const float* __restrict__ W_hh,
                       float* __restrict__ hA, float* __restrict__ cA,
                       float4* __restrict__ Wih4, float4* __restrict__ Whh4,
                       uint2* __restrict__ subs, unsigned int* __restrict__ bar_mem) {
  int tid = blockIdx.x * blockDim.x + threadIdx.x;
  int nthr = gridDim.x * blockDim.x;
  if (tid < 8 * 64 + 64)  // group lines + leader cnt + release
    __hip_atomic_store(bar_mem + tid, 0u, __ATOMIC_RELAXED, __HIP_MEMORY_SCOPE_AGENT);
  for (int i = tid; i < NPART * NBATCH * NHID; i += nthr) {
    hA[i] = h0[i];
    cA[i] = c0[i];
  }
  // Wih4[e*256 + j] = (W_ih[j,e], W_ih[256+j,e], W_ih[512+j,e], W_ih[768+j,e])
  for (int i = tid; i < NEIN * NHID; i += nthr) {
    int e = i >> 8, j = i & 255;
    Wih4[i] = make_float4(W_ih[j * NEIN + e], W_ih[(256 + j) * NEIN + e],
                          W_ih[(512 + j) * NEIN + e], W_ih[(768 + j) * NEIN + e]);
  }
  // Whh4[k*256 + j] = (W_hh[j,k], W_hh[256+j,k], W_hh[512+j,k], W_hh[768+j,k])
  for (int i = tid; i < NHID * NHID; i += nthr) {
    int k = i >> 8, j = i & 255;
    Whh4[i] = make_float4(W_hh[j * NHID + k], W_hh[(256 + j) * NHID + k],
                          W_hh[(512 + j) * NHID + k], W_hh[(768 + j) * NHID + k]);
  }
  if (tid < NSEQ) {
    // threefry_partitionable split: key' = tf(key,(0,0)), sub = tf(key,(0,1))
    uint32_t k0u = 0u, k1u = 42u, sx = 0u, sy = 0u;
    for (int i = 0; i <= tid; ++i) {
      uint32_t s0 = 0u, s1 = 1u; threefry2x32(k0u, k1u, s0, s1);
      uint32_t n0 = 0u, n1 = 0u; threefry2x32(k0u, k1u, n0, n1);
      sx = s0; sy = s1; k0u = n0; k1u = n1;
    }
    subs[tid] = make_uint2(sx, sy);
  }
}

// Stage the full batch h (64 x 256 floats) into LDS via pipelined 16B
// device-coherent loads. Pure copy -> values identical to r7's agent staging.
__device__ __forceinline__ void stage_h1(const float* __restrict__ hsrc, int b,
                                         float (*h1_s)[NHID]) {
  const int tid = threadIdx.x;
  f32x4 tmp[16];
#pragma unroll
  for (int k = 0; k < 16; ++k) {
    int i = tid + k * 256;  // 0..4095 over 64 rows x 64 float4
    int q = i >> 6, c4 = i & 63;
    dc_load16(tmp[k], hsrc + (q * NBATCH + b) * NHID + (c4 << 2));
  }
  dc_drain();
#pragma unroll
  for (int k = 0; k < 16; ++k) {
    int i = tid + k * 256;
    int q = i >> 6, c4 = i & 63;
    *(f32x4*)&h1_s[q][c4 << 2] = tmp[k];
  }
  __syncthreads();
}

// pf phase for step tm1 (math verbatim r6/r7, h1 sourced from LDS). Computed
// redundantly by every block of batch b; only is_des writes outputs.
__device__ __forceinline__ void pf_phase(
    int tm1, int b, bool is_des, const float* __restrict__ obs,
    const float* __restrict__ W_obs, const float* __restrict__ b_obs_p,
    const float* __restrict__ W_out, const float* __restrict__ b_out_p,
    const uint2* __restrict__ subs, float* __restrict__ d_out,
    float (*h1_s)[NHID], float* logp_s, float* p1_s, float* lg_s, float* e_s,
    float* p_cur_s, int* idx_s, float* lx_s, float* ysum_s) {
  const int tid = threadIdx.x;
  const int lane = tid & 63;
  const int wv = tid >> 6;

  if (wv == 0) {
    float v = obs[(b * NSEQ + tm1) * NEIN + lane] * W_obs[lane];
#pragma unroll
    for (int off = 32; off > 0; off >>= 1) v += __shfl_down(v, off, 64);
    if (lane == 0) *lx_s = v + b_obs_p[0];
  }
  for (int qq = 0; qq < 16; ++qq) {
    int q = wv * 16 + qq;
    float hp = 0.f;
#pragma unroll
    for (int m = 0; m < 4; ++m)
      hp += h1_s[q][m * 64 + lane] * W_obs[NEIN + m * 64 + lane];
#pragma unroll
    for (int off = 32; off > 0; off >>= 1) hp += __shfl_down(hp, off, 64);
    if (lane == 0) logp_s[q] = hp;
  }
  __syncthreads();

  if (wv == 0) {
    float x = logp_s[lane] + *lx_s + p_cur_s[lane];
    float m = x;
#pragma unroll
    for (int off = 32; off > 0; off >>= 1) {
      float o = __shfl_xor(m, off, 64);
      m = o > m ? o : m;
    }
    float s = expf(x - m);
#pragma unroll
    for (int off = 32; off > 0; off >>= 1) s += __shfl_xor(s, off, 64);
    float p1 = x - m - logf(s);
    p1_s[lane] = p1;
    lg_s[lane] = logf(0.1f * expf(p1) + 0.9f / 64.f);
  }
  __syncthreads();

  // categorical: partitionable random_bits, gumbel argmax
  const uint2 sub = subs[tm1];
  for (int qq = 0; qq < 16; ++qq) {
    int q = wv * 16 + qq;
    uint32_t x0 = 0u;
    uint32_t x1 = (uint32_t)((q * NBATCH + b) * NPART + lane);
    threefry2x32(sub.x, sub.y, x0, x1);
    uint32_t bits = x0 ^ x1;
    uint32_t mant = bits >> 9;
    float u = (mant == 0u) ? 1.17549435e-38f
                           : (float)mant * 1.1920928955078125e-07f;
    float g = -logf(-logf(u));
    float v = g + lg_s[lane];
    int id = lane;
#pragma unroll
    for (int off = 32; off > 0; off >>= 1) {
      float ov = __shfl_xor(v, off, 64);
      int oi = __shfl_xor(id, off, 64);
      if (ov > v || (ov == v && oi < id)) { v = ov; id = oi; }
    }
    if (lane == 0) idx_s[q] = id;
  }
  __syncthreads();

  if (wv == 0) {
    int src = idx_s[lane];
    float wn = 0.1f * expf(p1_s[src]) + 0.9f / 64.f;
    float lw = logf(wn);
    float m = lw;
#pragma unroll
    for (int off = 32; off > 0; off >>= 1) {
      float o = __shfl_xor(m, off, 64);
      m = o > m ? o : m;
    }
    float s = expf(lw - m);
#pragma unroll
    for (int off = 32; off > 0; off >>= 1) s += __shfl_xor(s, off, 64);
    float pn = lw - m - logf(s);
    p_cur_s[lane] = pn;
    e_s[lane] = expf(pn);
  }
  __syncthreads();

  // pf_out + deterministic y reduction (designated block only)
  if (is_des) {
    float yp = 0.f;
    for (int qq = 0; qq < 16; ++qq) {
      int q = wv * 16 + qq;
      int srow = idx_s[q];
      float pd = 0.f;
#pragma unroll
      for (int m = 0; m < 4; ++m)
        pd += h1_s[srow][m * 64 + lane] * W_out[m * 64 + lane];
#pragma unroll
      for (int off = 32; off > 0; off >>= 1) pd += __shfl_down(pd, off, 64);
      if (lane == 0) {
        d_out[NSEQ * NBATCH + tm1 * (NPART * NBATCH) + q * NBATCH + b] =
            lreluf(pd + b_out_p[0]);
        yp += e_s[q] * pd;
      }
    }
    if (lane == 0) ysum_s[wv] = yp;
    __syncthreads();
    if (tid == 0) {
      float y = ((ysum_s[0] + ysum_s[1]) + ysum_s[2]) + ysum_s[3];
      d_out[tm1 * NBATCH + b] = lreluf(y + b_out_p[0]);
    }
  }
}

// ---------------- persistent kernel: all 128 steps, ONE barrier/step ---------
// 256 blocks x 256 threads, 1 block/CU. bid = b*8 + qg*2 + cbp.
// Structure identical to validated r7; only access mechanics changed.
__global__ __launch_bounds__(256, 1)
void k_persist(const float* __restrict__ obs,
               float* __restrict__ hA, float* __restrict__ hB,
               float* __restrict__ cA, float* __restrict__ cB,
               const float4* __restrict__ Wih4, const float4* __restrict__ Whh4,
               const float* __restrict__ b_ih, const float* __restrict__ b_hh,
               const float* __restrict__ W_obs, const float* __restrict__ b_obs_p,
               const float* __restrict__ W_out, const float* __restrict__ b_out_p,
               const uint2* __restrict__ subs, unsigned int* __restrict__ bar_mem,
               float* __restrict__ d_out) {
  __shared__ __align__(16) float h1_s[NPART][NHID];  // 64 KB: full batch h
  __shared__ __align__(16) float c_s[16][128];       // 8 KB: gathered c tile
  __shared__ float4 Wbuf[32 * 64];                   // 32 KB
  __shared__ float obs_s[NEIN];
  __shared__ float logp_s[NPART], p1_s[NPART], lg_s[NPART], e_s[NPART],
      p_cur_s[NPART];
  __shared__ int idx_s[NPART];
  __shared__ float lx_s, ysum_s[4];

  unsigned int* grp_cnt = bar_mem;           // 8 lines x 64 u32
  unsigned int* lead_cnt = bar_mem + 8 * 64;
  unsigned int* release = bar_mem + 8 * 64 + 16;

  const int tid = threadIdx.x;
  const int bid = blockIdx.x;
  const int cbp = bid & 1;
  const int qg = (bid >> 1) & 3;
  const int b = bid >> 3;
  const bool is_des = ((bid & 7) == 0);
  const int lane = tid & 63;
  const int wv = tid >> 6;

  if (tid < NPART) p_cur_s[tid] = -4.1588830833596715f;  // fp32(log(1/64))

  for (int t = 0; t < NSEQ; ++t) {
    const float* hsrc = (t & 1) ? hB : hA;   // h written at t-1 (t=0: h0)
    const float* csrc = (t & 1) ? cB : cA;
    float* hdst = (t & 1) ? hA : hB;
    float* cdst = (t & 1) ? cA : cB;

    stage_h1(hsrc, b, h1_s);

    if (t == 0) {
      if (tid < NPART) idx_s[tid] = tid;  // identity resample for t=0
      __syncthreads();
    } else {
      pf_phase(t - 1, b, is_des, obs, W_obs, b_obs_p, W_out, b_out_p, subs,
               d_out, h1_s, logp_s, p1_s, lg_s, e_s, p_cur_s, idx_s, &lx_s,
               ysum_s);
    }

    // stage gathered c tile: rows = idx_s[qg*16 + r], cols = cbp*128..+128
    {
      f32x4 t0, t1;
      int i0 = tid, i1 = tid + 256;  // 512 float4 = 16 rows x 32 float4
      int r0 = i0 >> 5, c40 = i0 & 31;
      int r1 = i1 >> 5, c41 = i1 & 31;
      dc_load16(t0, csrc + (idx_s[qg * 16 + r0] * NBATCH + b) * NHID +
                        cbp * 128 + (c40 << 2));
      dc_load16(t1, csrc + (idx_s[qg * 16 + r1] * NBATCH + b) * NHID +
                        cbp * 128 + (c41 << 2));
      dc_drain();
      *(f32x4*)&c_s[r0][c40 << 2] = t0;
      *(f32x4*)&c_s[r1][c41 << 2] = t1;
    }

    // ======== GEMM + LSTM pointwise (obs[t]) ========
    if (tid < NEIN) obs_s[tid] = obs[(b * NSEQ + t) * NEIN + tid];
    __syncthreads();

    const int rg = wv;  // wave id = row group (4 rows each)
    int srow[4];
#pragma unroll
    for (int rr = 0; rr < 4; ++rr) srow[rr] = idx_s[qg * 16 + rg * 4 + rr];

    for (int cbi = 0; cbi < 2; ++cbi) {
      const int cb = cbp * 2 + cbi;
      const int jglob = cb * 64 + lane;

      float xb[4];
      xb[0] = b_ih[jglob] + b_hh[jglob];
      xb[1] = b_ih[jglob + 256] + b_hh[jglob + 256];
      xb[2] = b_ih[jglob + 512] + b_hh[jglob + 512];
      xb[3] = b_ih[jglob + 768] + b_hh[jglob + 768];
#pragma unroll 8
      for (int e = 0; e < NEIN; ++e) {
        float xv = obs_s[e];
        float4 w = Wih4[e * NHID + jglob];
        xb[0] += xv * w.x;
        xb[1] += xv * w.y;
        xb[2] += xv * w.z;
        xb[3] += xv * w.w;
      }

      float acc[4][4];
#pragma unroll
      for (int rr = 0; rr < 4; ++rr)
#pragma unroll
        for (int g = 0; g < 4; ++g) acc[rr][g] = 0.f;

      const float4* hrow4[4];
#pragma unroll
      for (int rr = 0; rr < 4; ++rr) hrow4[rr] = (const float4*)h1_s[srow[rr]];

      for (int c = 0; c < 8; ++c) {  // 8 chunks of 32 k
        const int k0 = c * 32;
        __syncthreads();             // Wbuf reuse guard
        for (int i = tid; i < 32 * 64; i += 256)
          Wbuf[i] = Whh4[(k0 + (i >> 6)) * NHID + cb * 64 + (i & 63)];
        __syncthreads();
#pragma unroll
        for (int k4 = 0; k4 < 8; ++k4) {  // 4 k at a time
          float4 h4[4];
#pragma unroll
          for (int rr = 0; rr < 4; ++rr) h4[rr] = hrow4[rr][(k0 >> 2) + k4];
#pragma unroll
          for (int kk = 0; kk < 4; ++kk) {
            float4 w = Wbuf[(k4 * 4 + kk) * 64 + lane];
#pragma unroll
            for (int rr = 0; rr < 4; ++rr) {
              float hv = ((const float*)&h4[rr])[kk];
              acc[rr][0] += hv * w.x;
              acc[rr][1] += hv * w.y;
              acc[rr][2] += hv * w.z;
              acc[rr][3] += hv * w.w;
            }
          }
        }
      }

#pragma unroll
      for (int rr = 0; rr < 4; ++rr) {
        int q = qg * 16 + rg * 4 + rr;
        int n = q * NBATCH + b;
        float iv = acc[rr][0] + xb[0];
        float fv = acc[rr][1] + xb[1];
        float gv = acc[rr][2] + xb[2];
        float ov = acc[rr][3] + xb[3];
        float cp = c_s[rg * 4 + rr][cbi * 64 + lane];
        float si = 1.f / (1.f + expf(-iv));
        float sf = 1.f / (1.f + expf(-fv));
        float so = 1.f / (1.f + expf(-ov));
        float c1 = sf * cp + si * tanhf(gv);
        float h1 = so * tanhf(c1);
        dc_store4(hdst + n * NHID + jglob, h1);
        dc_store4(cdst + n * NHID + jglob, c1);
      }
      __syncthreads();  // h1_s/Wbuf reuse for cbi=1
    }

    grid_barrier(grp_cnt, lead_cnt, release, bid, (unsigned int)(t + 1));
  }

  // tail: pf for t = 127 (h written at t=127 lives in hA since 127&1==1)
  stage_h1(hA, b, h1_s);
  pf_phase(NSEQ - 1, b, is_des, obs, W_obs, b_obs_p, W_out, b_out_p, subs,
           d_out, h1_s, logp_s, p1_s, lg_s, e_s, p_cur_s, idx_s, &lx_s,
           ysum_s);
}

extern "C" void kernel_launch(void* const* d_in, const int* in_sizes, int n_in,
                              void* d_out, int out_size, void* d_ws, size_t ws_size,
                              hipStream_t stream) {
  const float* obs   = (const float*)d_in[0];
  const float* h0    = (const float*)d_in[1];
  const float* c0    = (const float*)d_in[2];
  const float* W_ih  = (const float*)d_in[3];
  const float* b_ih  = (const float*)d_in[4];
  const float* W_hh  = (const float*)d_in[5];
  const float* b_hh  = (const float*)d_in[6];
  const float* W_obs = (const float*)d_in[7];
  const float* b_obs = (const float*)d_in[8];
  const float* W_out = (const float*)d_in[9];
  const float* b_out = (const float*)d_in[10];
  float* out = (float*)d_out;

  char* w = (char*)d_ws;
  const size_t state = (size_t)NPART * NBATCH * NHID * sizeof(float);  // 2 MB
  float* hA = (float*)w;              w += state;
  float* hB = (float*)w;              w += state;
  float* cA = (float*)w;              w += state;
  float* cB = (float*)w;              w += state;
  uint2* subs = (uint2*)w;            w += NSEQ * sizeof(uint2);
  float4* Wih4 = (float4*)w;          w += NEIN * NHID * sizeof(float4);
  float4* Whh4 = (float4*)w;          w += NHID * NHID * sizeof(float4);
  unsigned int* bar_mem = (unsigned int*)w;  w += (8 * 64 + 64) * sizeof(unsigned int);

  k_prep<<<dim3(256), dim3(256), 0, stream>>>(h0, c0, W_ih, W_hh, hA, cA, Wih4, Whh4,
                                              subs, bar_mem);
  k_persist<<<dim3(NBLK), dim3(256), 0, stream>>>(
      obs, hA, hB, cA, cB, Wih4, Whh4, b_ih, b_hh, W_obs, b_obs, W_out, b_out,
      subs, bar_mem, out);
}